// Round 1
// 78.009 us; speedup vs baseline: 1.4286x; 1.4286x over previous
//
#include <hip/hip_runtime.h>
#include <cstdint>
#include <cstring>

// ---------------------------------------------------------------------------
// LinearBNNoise: x[65536,784] -> Linear(784,48) -> BN -> +noise(key 1234) -> ReLU
//                -> Linear(48,24) -> BN -> +noise(key 5678) -> ReLU -> Linear(24,10)
// GEMM1: MFMA bf16 16x16x32, no LDS, no barriers in K-loop (HBM-bound on the
// 205 MB x read). BN finalize folded into layer2/layer3 (each block recomputes
// deterministically from the per-feature sums). 4 dispatches total.
// Noise reproduces JAX threefry2x32 partitionable mode (bits = x0 ^ x1).
// R1 changes vs baseline (111.4 us):
//  - A-fragment f32->bf16 packing via v_cvt_pk_bf16_f32 (1 instr / 2 floats,
//    same RNE) instead of 7-op bit-twiddle: K-loop VALU 28 -> 4 ops/step.
//  - per-feature stats atomics spread over 8 XCD-strided replicas
//    (blockIdx&7) to kill same-cacheline serialization of ~100K atomics;
//    replicas summed in the per-block BN finalize.
//  - erfinv: w = -__logf(1-x*x) instead of libm log1pf (-~25 VALU ops per
//    noise value; |u|<=1-2^-23 so 1-u^2 >= ~2^-22, error ~1e-6 in w).
// ---------------------------------------------------------------------------

constexpr int MROWS = 65536;
constexpr int KDIM  = 784;
constexpr int KPAD  = 800;   // 25 * 32, zero-padded bf16 weights
constexpr int F1 = 48, F2 = 24, F3 = 10;

using frag_ab = __attribute__((ext_vector_type(8))) short;  // 8 bf16 (4 VGPRs)
using frag_cd = __attribute__((ext_vector_type(4))) float;  // 4 fp32

union UB { uint4 u; frag_ab f; };

// ---------------- threefry2x32 (20 rounds) ----------------
__device__ __forceinline__ uint32_t rotl32(uint32_t v, int r) {
  return (v << r) | (v >> (32 - r));
}

// XOR of both output words of threefry2x32(key=(k0,k1), counts=(0, ctr))
__device__ __forceinline__ uint32_t tf_mix(uint32_t k0, uint32_t k1, uint32_t ctr) {
  uint32_t ks2 = k0 ^ k1 ^ 0x1BD11BDAu;
  uint32_t x0 = k0;
  uint32_t x1 = ctr + k1;
#define TFR(r) { x0 += x1; x1 = rotl32(x1, r); x1 ^= x0; }
  TFR(13) TFR(15) TFR(26) TFR(6)
  x0 += k1;  x1 += ks2 + 1u;
  TFR(17) TFR(29) TFR(16) TFR(24)
  x0 += ks2; x1 += k0 + 2u;
  TFR(13) TFR(15) TFR(26) TFR(6)
  x0 += k0;  x1 += k1 + 3u;
  TFR(17) TFR(29) TFR(16) TFR(24)
  x0 += k1;  x1 += ks2 + 4u;
  TFR(13) TFR(15) TFR(26) TFR(6)
  x0 += ks2; x1 += k0 + 5u;
#undef TFR
  return x0 ^ x1;
}

// XLA ErfInv f32 (Giles) — exact coefficients. Fast log: u in (-1,1) with
// |u| <= 1-2^-23 so 1-u*u >= ~2^-22; -__logf(1-u*u) matches log1pf(-u*u)
// to ~1e-6 absolute in w, invisible at the output tolerance.
__device__ __forceinline__ float erfinv_f32(float x) {
  float t = fmaxf(1.0f - x * x, 1.0e-30f);
  float w = -__logf(t);
  float p;
  if (w < 5.0f) {
    w = w - 2.5f;
    p = 2.81022636e-08f;
    p = fmaf(p, w, 3.43273939e-07f);
    p = fmaf(p, w, -3.5233877e-06f);
    p = fmaf(p, w, -4.39150654e-06f);
    p = fmaf(p, w, 0.00021858087f);
    p = fmaf(p, w, -0.00125372503f);
    p = fmaf(p, w, -0.00417768164f);
    p = fmaf(p, w, 0.246640727f);
    p = fmaf(p, w, 1.50140941f);
  } else {
    w = sqrtf(w) - 3.0f;
    p = -0.000200214257f;
    p = fmaf(p, w, 0.000100950558f);
    p = fmaf(p, w, 0.00134934322f);
    p = fmaf(p, w, -0.00367342844f);
    p = fmaf(p, w, 0.00573950773f);
    p = fmaf(p, w, -0.0076224613f);
    p = fmaf(p, w, 0.00943887047f);
    p = fmaf(p, w, 1.00167406f);
    p = fmaf(p, w, 2.83297682f);
  }
  return p * x;
}

__device__ __forceinline__ float noise_normal(uint32_t k0, uint32_t k1, uint32_t ctr) {
  uint32_t bits = tf_mix(k0, k1, ctr);
  float f = __uint_as_float((bits >> 9) | 0x3f800000u) - 1.0f; // [0,1)
  const float lo = -0.99999994f;
  float u = fmaxf(lo, f * 2.0f + lo);
  return 1.41421356f * erfinv_f32(u);
}

// pack two fp32 -> two bf16 (RNE) into one uint32 (low = a) — prep only
__device__ __forceinline__ uint32_t pkbf(float a, float b) {
  uint32_t ua = __float_as_uint(a); ua += 0x7fffu + ((ua >> 16) & 1u);
  uint32_t ub = __float_as_uint(b); ub += 0x7fffu + ((ub >> 16) & 1u);
  return (ua >> 16) | (ub & 0xffff0000u);
}

// hardware packed f32->bf16 (RNE), low word = a. gfx950 has no builtin (m240).
__device__ __forceinline__ uint32_t cvtpk(float a, float b) {
  uint32_t r;
  asm("v_cvt_pk_bf16_f32 %0, %1, %2" : "=v"(r) : "v"(a), "v"(b));
  return r;
}

// ---------------- prep: w1 -> bf16 [48,800] zero-padded; zero stats block -------
__global__ void k_prep(const float* __restrict__ w1, ushort* __restrict__ wb1,
                       float* __restrict__ st) {
  int i = blockIdx.x * 256 + threadIdx.x;
  if (i < 2048) st[i] = 0.f;     // 8-replica stats block
  if (i >= F1 * KPAD) return;
  int n = i / KPAD, k = i - n * KPAD;
  float v = (k < KDIM) ? w1[n * KDIM + k] : 0.f;
  uint32_t u = __float_as_uint(v);
  u += 0x7fffu + ((u >> 16) & 1u);
  wb1[i] = (ushort)(u >> 16);
}

// ---------------- Kernel A: MFMA bf16 GEMM1, no-LDS, + per-feature stats -------
// Block: 256 thr = 4 waves, 64 rows. Wave w: rows w*16..w*16+15 x 48 cols.
// K loop: 25 steps of 32. A direct from global (2x dwordx4/lane), reg prefetch.
// Stats land in replica (blockIdx & 7) to decontend the atomics.
__global__ __launch_bounds__(256, 4) void k_gemm1(
    const float* __restrict__ x, const ushort* __restrict__ wb1,
    const float* __restrict__ b1, float* __restrict__ h1,
    float* __restrict__ fsum, float* __restrict__ fssq) {
  __shared__ float reds[4][48], redq[4][48];

  const int t = threadIdx.x;
  const int w = t >> 6;
  const int l = t & 63;
  const int lane16 = l & 15;
  const int quad = l >> 4;
  const int rowbase = blockIdx.x * 64;
  const int myrow = rowbase + w * 16 + lane16;   // A-operand row for this lane

  frag_cd acc[3];
#pragma unroll
  for (int ct = 0; ct < 3; ++ct)
#pragma unroll
    for (int r = 0; r < 4; ++r) acc[ct][r] = 0.f;

  // A: lane reads x[myrow][s*32 + quad*8 .. +7]
  const float* ap = x + (size_t)myrow * KDIM + quad * 8;
  // B: lane's column n = ct*16 + lane16, 8 contiguous k at quad*8
  const ushort* bp0 = wb1 + (size_t)(0 * 16 + lane16) * KPAD + quad * 8;
  const ushort* bp1 = wb1 + (size_t)(1 * 16 + lane16) * KPAD + quad * 8;
  const ushort* bp2 = wb1 + (size_t)(2 * 16 + lane16) * KPAD + quad * 8;

  float4 ca0 = *(const float4*)(ap);
  float4 ca1 = *(const float4*)(ap + 4);
  uint4 cb0 = *(const uint4*)(bp0);
  uint4 cb1 = *(const uint4*)(bp1);
  uint4 cb2 = *(const uint4*)(bp2);

  for (int s = 0; s < 25; ++s) {
    float4 na0 = make_float4(0.f, 0.f, 0.f, 0.f);
    float4 na1 = na0;
    uint4 nb0 = make_uint4(0, 0, 0, 0), nb1 = nb0, nb2 = nb0;
    if (s < 24) {
      const int ko = (s + 1) * 32;
      if (ko + quad * 8 + 8 <= KDIM) {   // tail: s=24, quads 2..3 stay zero
        na0 = *(const float4*)(ap + ko);
        na1 = *(const float4*)(ap + ko + 4);
      }
      nb0 = *(const uint4*)(bp0 + ko);   // wb1 zero-padded to 800
      nb1 = *(const uint4*)(bp1 + ko);
      nb2 = *(const uint4*)(bp2 + ko);
    }
    UB a;
    a.u.x = cvtpk(ca0.x, ca0.y);
    a.u.y = cvtpk(ca0.z, ca0.w);
    a.u.z = cvtpk(ca1.x, ca1.y);
    a.u.w = cvtpk(ca1.z, ca1.w);
    UB b;
    b.u = cb0; acc[0] = __builtin_amdgcn_mfma_f32_16x16x32_bf16(a.f, b.f, acc[0], 0, 0, 0);
    b.u = cb1; acc[1] = __builtin_amdgcn_mfma_f32_16x16x32_bf16(a.f, b.f, acc[1], 0, 0, 0);
    b.u = cb2; acc[2] = __builtin_amdgcn_mfma_f32_16x16x32_bf16(a.f, b.f, acc[2], 0, 0, 0);
    ca0 = na0; ca1 = na1; cb0 = nb0; cb1 = nb1; cb2 = nb2;
  }

  // epilogue: bias, store h1, per-feature sum/ssq
  float bias[3];
#pragma unroll
  for (int ct = 0; ct < 3; ++ct) bias[ct] = b1[ct * 16 + lane16];
  float psum[3] = {0.f, 0.f, 0.f}, pssq[3] = {0.f, 0.f, 0.f};
#pragma unroll
  for (int r = 0; r < 4; ++r) {
    const int grow = rowbase + w * 16 + quad * 4 + r;   // C row = quad*4+reg
#pragma unroll
    for (int ct = 0; ct < 3; ++ct) {
      float v = acc[ct][r] + bias[ct];
      h1[(size_t)grow * F1 + ct * 16 + lane16] = v;     // C col = lane16
      psum[ct] += v;
      pssq[ct] += v * v;
    }
  }
#pragma unroll
  for (int ct = 0; ct < 3; ++ct) {
    psum[ct] += __shfl_xor(psum[ct], 16, 64);
    psum[ct] += __shfl_xor(psum[ct], 32, 64);
    pssq[ct] += __shfl_xor(pssq[ct], 16, 64);
    pssq[ct] += __shfl_xor(pssq[ct], 32, 64);
  }
  if (quad == 0) {
#pragma unroll
    for (int ct = 0; ct < 3; ++ct) {
      reds[w][ct * 16 + lane16] = psum[ct];
      redq[w][ct * 16 + lane16] = pssq[ct];
    }
  }
  __syncthreads();
  if (t < F1) {
    float s = reds[0][t] + reds[1][t] + reds[2][t] + reds[3][t];
    float q = redq[0][t] + redq[1][t] + redq[2][t] + redq[3][t];
    const int rep = blockIdx.x & 7;
    atomicAdd(&fsum[rep * 48 + t], s);
    atomicAdd(&fssq[rep * 48 + t], q);
  }
}

// ---------------- Kernel C: finalize-BN1 + noise + ReLU -> GEMM2 -> stats2 -----
// Each block redundantly (deterministically) finalizes BN params from the 8
// stat replicas.
__global__ __launch_bounds__(256) void k_layer2(
    const float* __restrict__ h1, const float* __restrict__ w2,
    const float* __restrict__ b2, const float* __restrict__ gamma1,
    const float* __restrict__ beta1, const float* __restrict__ fsum,
    const float* __restrict__ fssq, float u1,
    float* __restrict__ h2, float* __restrict__ fsum2, float* __restrict__ fssq2,
    uint32_t kna, uint32_t knb) {
  __shared__ float a1s[64][49];
  __shared__ float w2s[48][25];
  __shared__ float h2s[64][25];
  __shared__ float bnp[4][48];
  __shared__ float scal[2];

  const int t = threadIdx.x;
  const int rowbase = blockIdx.x * 64;

  // finalize BN1 stats (identical arithmetic in every block)
  float cm = 0.f, cs = 0.f;
  if (t < F1) {
    float s0 = 0.f, q0 = 0.f;
#pragma unroll
    for (int rp = 0; rp < 8; ++rp) { s0 += fsum[rp * 48 + t]; q0 += fssq[rp * 48 + t]; }
    float m = s0 * (1.f / 65536.f);
    float v = q0 * (1.f / 65536.f) - m * m;
    float r = rsqrtf(v + 1e-5f);
    float g = gamma1[t], b = beta1[t];
    bnp[0][t] = m; bnp[1][t] = r; bnp[2][t] = g; bnp[3][t] = b;
    cm = b;
    cs = g * g * r * r * v + b * b;
  }
  if (t < 64) {
#pragma unroll
    for (int off = 32; off > 0; off >>= 1) {
      cm += __shfl_down(cm, off, 64);
      cs += __shfl_down(cs, off, 64);
    }
    if (t == 0) {
      float m = cm / (float)F1;
      float SS = 65536.f * cs;
      float Ntot = 65536.f * (float)F1;
      float s2 = (SS - Ntot * m * m) / (Ntot - 1.f);  // ddof=1
      scal[0] = m;
      scal[1] = sqrtf(s2) * u1;
    }
  }
  for (int e = t; e < F2 * 48; e += 256) {
    int c = e / 48, k = e - c * 48;
    w2s[k][c] = w2[e];
  }
  __syncthreads();
  const float m1 = scal[0], su1 = scal[1];

  const int rr = t >> 2;
  const int cc0 = (t & 3) * 12;
  const int grow = rowbase + rr;
  const float* hrow = h1 + (size_t)grow * F1 + cc0;
#pragma unroll
  for (int jj = 0; jj < 12; jj += 4) {
    float4 hv = *(const float4*)(hrow + jj);
    float vv[4] = {hv.x, hv.y, hv.z, hv.w};
#pragma unroll
    for (int q = 0; q < 4; ++q) {
      int c = cc0 + jj + q;
      float bn = (vv[q] - bnp[0][c]) * bnp[1][c] * bnp[2][c] + bnp[3][c];
      uint32_t ctr = (uint32_t)grow * 48u + (uint32_t)c;
      float nz = noise_normal(kna, knb, ctr);
      float val = bn + fmaf(su1, nz, m1);
      a1s[rr][c] = fmaxf(val, 0.f);
    }
  }
  __syncthreads();

  const int rr2 = t & 63;
  const int c0 = (t >> 6) * 6;
  float acc[6] = {0.f, 0.f, 0.f, 0.f, 0.f, 0.f};
#pragma unroll
  for (int k = 0; k < 48; ++k) {
    float a = a1s[rr2][k];
#pragma unroll
    for (int j = 0; j < 6; ++j)
      acc[j] = fmaf(a, w2s[k][c0 + j], acc[j]);
  }
#pragma unroll
  for (int j = 0; j < 6; ++j)
    h2s[rr2][c0 + j] = acc[j] + b2[c0 + j];
  __syncthreads();

  for (int e = t; e < 64 * F2; e += 256) {
    int r2 = e / 24, c2 = e - r2 * 24;
    h2[(size_t)rowbase * F2 + e] = h2s[r2][c2];
  }
  if (t < F2) {
    float s = 0.f, q = 0.f;
    for (int r2 = 0; r2 < 64; ++r2) {
      float v = h2s[r2][t];
      s += v; q += v * v;
    }
    const int rep = blockIdx.x & 7;
    atomicAdd(&fsum2[rep * 24 + t], s);
    atomicAdd(&fssq2[rep * 24 + t], q);
  }
}

// ---------------- Kernel E: finalize-BN2 + noise + ReLU -> GEMM3 -> out --------
__global__ __launch_bounds__(256) void k_layer3(
    const float* __restrict__ h2, const float* __restrict__ w3,
    const float* __restrict__ b3, const float* __restrict__ gamma2,
    const float* __restrict__ beta2, const float* __restrict__ fsum2,
    const float* __restrict__ fssq2, float u2,
    float* __restrict__ out, uint32_t kna, uint32_t knb) {
  __shared__ float a2s[64][25];
  __shared__ float w3s[24][10];
  __shared__ float bnp[4][24];
  __shared__ float scal[2];

  const int t = threadIdx.x;
  const int rowbase = blockIdx.x * 64;

  float cm = 0.f, cs = 0.f;
  if (t < F2) {
    float s0 = 0.f, q0 = 0.f;
#pragma unroll
    for (int rp = 0; rp < 8; ++rp) { s0 += fsum2[rp * 24 + t]; q0 += fssq2[rp * 24 + t]; }
    float m = s0 * (1.f / 65536.f);
    float v = q0 * (1.f / 65536.f) - m * m;
    float r = rsqrtf(v + 1e-5f);
    float g = gamma2[t], b = beta2[t];
    bnp[0][t] = m; bnp[1][t] = r; bnp[2][t] = g; bnp[3][t] = b;
    cm = b;
    cs = g * g * r * r * v + b * b;
  }
  if (t < 64) {
#pragma unroll
    for (int off = 32; off > 0; off >>= 1) {
      cm += __shfl_down(cm, off, 64);
      cs += __shfl_down(cs, off, 64);
    }
    if (t == 0) {
      float m = cm / (float)F2;
      float SS = 65536.f * cs;
      float Ntot = 65536.f * (float)F2;
      float s2 = (SS - Ntot * m * m) / (Ntot - 1.f);  // ddof=1
      scal[0] = m;
      scal[1] = sqrtf(s2) * u2;
    }
  }
  if (t < F3 * F2) {
    int c = t / 24, k = t - c * 24;
    w3s[k][c] = w3[t];
  }
  __syncthreads();
  const float m2 = scal[0], su2 = scal[1];

  for (int e = t; e < 64 * F2; e += 256) {
    int r = e / 24, c = e - r * 24;
    float v = h2[(size_t)rowbase * F2 + e];
    float bn = (v - bnp[0][c]) * bnp[1][c] * bnp[2][c] + bnp[3][c];
    uint32_t ctr = (uint32_t)(rowbase * F2 + e);
    float nz = noise_normal(kna, knb, ctr);
    float val = bn + fmaf(su2, nz, m2);
    a2s[r][c] = fmaxf(val, 0.f);
  }
  __syncthreads();

  if (t < 128) {
    const int rr = t & 63;
    const int c0 = (t >> 6) * 5;
    float acc[5] = {0.f, 0.f, 0.f, 0.f, 0.f};
#pragma unroll
    for (int k = 0; k < 24; ++k) {
      float a = a2s[rr][k];
#pragma unroll
      for (int j = 0; j < 5; ++j)
        acc[j] = fmaf(a, w3s[k][c0 + j], acc[j]);
    }
    size_t ob = (size_t)(rowbase + rr) * F3 + c0;
#pragma unroll
    for (int j = 0; j < 5; ++j) out[ob + j] = acc[j] + b3[c0 + j];
  }
}

// ---------------- host threefry ----------------
static void host_tf(uint32_t k0, uint32_t k1, uint32_t c0, uint32_t c1,
                    uint32_t& o0, uint32_t& o1) {
  uint32_t ks2 = k0 ^ k1 ^ 0x1BD11BDAu;
  uint32_t x0 = c0 + k0, x1 = c1 + k1;
  auto R = [&](int r) { x0 += x1; x1 = (x1 << r) | (x1 >> (32 - r)); x1 ^= x0; };
  R(13); R(15); R(26); R(6);  x0 += k1;  x1 += ks2 + 1u;
  R(17); R(29); R(16); R(24); x0 += ks2; x1 += k0 + 2u;
  R(13); R(15); R(26); R(6);  x0 += k0;  x1 += k1 + 3u;
  R(17); R(29); R(16); R(24); x0 += k1;  x1 += ks2 + 4u;
  R(13); R(15); R(26); R(6);  x0 += ks2; x1 += k0 + 5u;
  o0 = x0; o1 = x1;
}

static float host_uniform12(uint32_t seed) {
  uint32_t ka, kb, t0, t1;
  host_tf(0u, seed, 0u, 0u, ka, kb);     // foldlike split, ctr 0 -> ku
  host_tf(ka, kb, 0u, 0u, t0, t1);       // random_bits of shape ()
  uint32_t bits = t0 ^ t1;               // partitionable: XOR of both words
  uint32_t fb = (bits >> 9) | 0x3f800000u;
  float f;
  std::memcpy(&f, &fb, 4);
  return f;
}

extern "C" void kernel_launch(void* const* d_in, const int* in_sizes, int n_in,
                              void* d_out, int out_size, void* d_ws, size_t ws_size,
                              hipStream_t stream) {
  (void)in_sizes; (void)n_in; (void)out_size; (void)ws_size;
  const float* x      = (const float*)d_in[0];
  const float* w1     = (const float*)d_in[1];
  const float* b1     = (const float*)d_in[2];
  const float* gamma1 = (const float*)d_in[3];
  const float* beta1  = (const float*)d_in[4];
  const float* w2     = (const float*)d_in[5];
  const float* b2     = (const float*)d_in[6];
  const float* gamma2 = (const float*)d_in[7];
  const float* beta2  = (const float*)d_in[8];
  const float* w3     = (const float*)d_in[9];
  const float* b3     = (const float*)d_in[10];
  float* out = (float*)d_out;

  float* h1 = (float*)d_ws;                       // 65536*48
  float* h2 = h1 + (size_t)MROWS * F1;            // 65536*24
  float* st = h2 + (size_t)MROWS * F2;            // stats block (2048 floats)
  ushort* wb1 = (ushort*)(st + 2048);             // 48*800 bf16

  uint32_t kn1a, kn1b, kn2a, kn2b;
  host_tf(0u, 1234u, 0u, 1u, kn1a, kn1b);         // kn of foldlike split(key(1234))
  host_tf(0u, 5678u, 0u, 1u, kn2a, kn2b);         // kn of foldlike split(key(5678))
  float u1 = host_uniform12(1234u);
  float u2 = host_uniform12(5678u);

  // st layout (8 replicas each): fsum1[8][48]@0  fssq1[8][48]@384
  //                              fsum2[8][24]@768 fssq2[8][24]@960
  k_prep<<<(F1 * KPAD + 255) / 256, 256, 0, stream>>>(w1, wb1, st);
  k_gemm1<<<MROWS / 64, 256, 0, stream>>>(x, wb1, b1, h1, st + 0, st + 384);
  k_layer2<<<MROWS / 64, 256, 0, stream>>>(h1, w2, b2, gamma1, beta1,
                                           st + 0, st + 384, u1,
                                           h2, st + 768, st + 960, kn1a, kn1b);
  k_layer3<<<MROWS / 64, 256, 0, stream>>>(h2, w3, b3, gamma2, beta2,
                                           st + 768, st + 960, u2,
                                           out, kn2a, kn2b);
}